// Round 5
// baseline (487.963 us; speedup 1.0000x reference)
//
#include <hip/hip_runtime.h>
#include <math.h>

#define TPB 576  // 9 waves; one image per block

__device__ __forceinline__ float f4c(const float4 v, int p) {
    return (p == 0) ? v.x : ((p == 1) ? v.y : v.z);
}

// LDS arena (bytes):
//  s2v  float4[676]   @ 0      (10816)  conv2 out, 3 patches in .x/.y/.z, zero border
//  xs   float [784]   @ 10816  (3136)
//  buf  float4[2*676] @ 13952  (21632)  conv1 out (4ch packed), double buffered
//  pm   float4[24*25] @ 13952  (9600)   alias over buf[0] after channel loop
//  hist float [384]   @ 35584  (1536)
//  nrm  float [3]     @ 37120
//  lg   float [16]    @ 37136
__global__ __launch_bounds__(TPB) void fused_pipeline(
    const float* __restrict__ x,    // [N,784]
    const float* __restrict__ W1,   // [32,1,3,3]
    const float* __restrict__ b1,   // [32]
    const float* __restrict__ W2,   // [3,32,3,3]
    const float* __restrict__ b2,   // [3]
    const float* __restrict__ Wl,   // [10,384]
    const float* __restrict__ bl,   // [10]
    float* __restrict__ out)        // [N,10]
{
    __shared__ __align__(16) char arena[37200];
    float4* const s2v  = (float4*)(arena);
    float*  const xs   = (float*)(arena + 10816);
    float4* const buf  = (float4*)(arena + 13952);
    float4* const pm   = (float4*)(arena + 13952);
    float*  const hist = (float*)(arena + 35584);
    float*  const nrm  = (float*)(arena + 37120);
    float*  const lg   = (float*)(arena + 37136);

    const int n = blockIdx.x;
    const int t = threadIdx.x;

    // ---- stage x (float4 coalesced) + zero only the s2v border (100 cells) ----
    if (t < 196) ((float4*)xs)[t] = ((const float4*)(x + n * 784))[t];
    if (t < 100) {
        int idx;
        if (t < 26)      idx = t;                     // top row
        else if (t < 52) idx = 650 + (t - 26);        // bottom row
        else if (t < 76) idx = (t - 52 + 1) * 26;     // left col
        else             idx = (t - 76 + 1) * 26 + 25;// right col
        s2v[idx] = make_float4(0.f, 0.f, 0.f, 0.f);
    }
    __syncthreads();

    // ---- register-cache conv1 input taps ----
    const int p0i = t / 26, p0j = t % 26;
    float xn[9];
#pragma unroll
    for (int q = 0; q < 9; ++q)
        xn[q] = xs[(p0i + q / 3) * 28 + (p0j + q % 3)];
    const int p1 = 576 + t;
    const int p1i = p1 / 26, p1j = p1 % 26;
    float xn2[9];
    if (t < 100) {
#pragma unroll
        for (int q = 0; q < 9; ++q)
            xn2[q] = xs[(p1i + q / 3) * 28 + (p1j + q % 3)];
    }

    const int i2 = t / 24, j2 = t % 24;
    float acc[3] = {0.f, 0.f, 0.f};

    // precomputed bases: all inner LDS accesses use constant offsets
    const float4* const rb0 = buf + i2 * 26 + j2;        // conv2 read window, buffer 0
    const float4* const rb1 = rb0 + 676;                 // buffer 1
    float4* const wb0 = buf + t;                         // conv1 write, buffer 0
    float4* const wb1 = wb0 + 676;
    float4* const wq0 = buf + p1;                        // second-pixel write
    float4* const wq1 = wq0 + 676;

    auto conv1_step = [&](int c0, float4* wdst, float4* wdst2) {
        float4 v;
        float* vp = (float*)&v;
#pragma unroll
        for (int cc = 0; cc < 4; ++cc) {
            const float* w = W1 + (c0 + cc) * 9;   // wave-uniform -> s_load
            float s = b1[c0 + cc];
#pragma unroll
            for (int q = 0; q < 9; ++q) s = fmaf(w[q], xn[q], s);
            vp[cc] = fmaxf(s, 0.f);
        }
        *wdst = v;
        if (t < 100) {
            float4 v2;
            float* vp2 = (float*)&v2;
#pragma unroll
            for (int cc = 0; cc < 4; ++cc) {
                const float* w = W1 + (c0 + cc) * 9;
                float s = b1[c0 + cc];
#pragma unroll
                for (int q = 0; q < 9; ++q) s = fmaf(w[q], xn2[q], s);
                vp2[cc] = fmaxf(s, 0.f);
            }
            *wdst2 = v2;
        }
    };

    auto conv2_step = [&](int c0, const float4* r) {
#pragma unroll
        for (int di = 0; di < 3; ++di) {
            const float4 a0 = r[di * 26 + 0];   // ds_read_b128 offset:imm
            const float4 a1 = r[di * 26 + 1];
            const float4 a2 = r[di * 26 + 2];
#pragma unroll
            for (int k = 0; k < 3; ++k) {
                const float* w = W2 + k * 288 + c0 * 9 + di * 3;  // wave-uniform
                float s = acc[k];
                s = fmaf(w[0],  a0.x, s); s = fmaf(w[9],  a0.y, s);
                s = fmaf(w[18], a0.z, s); s = fmaf(w[27], a0.w, s);
                s = fmaf(w[1],  a1.x, s); s = fmaf(w[10], a1.y, s);
                s = fmaf(w[19], a1.z, s); s = fmaf(w[28], a1.w, s);
                s = fmaf(w[2],  a2.x, s); s = fmaf(w[11], a2.y, s);
                s = fmaf(w[20], a2.z, s); s = fmaf(w[29], a2.w, s);
                acc[k] = s;
            }
        }
    };

    // ---- fused conv1 -> conv2, 8 channels per unrolled iteration ----
#pragma unroll 1
    for (int cc2 = 0; cc2 < 4; ++cc2) {
        const int c0 = cc2 * 8;
        conv1_step(c0, wb0, wq0);
        __syncthreads();
        conv2_step(c0, rb0);
        conv1_step(c0 + 4, wb1, wq1);
        __syncthreads();
        conv2_step(c0 + 4, rb1);
    }

    // ---- conv2 bias; pack 3 patches into interior of zero-padded 26x26 ----
    s2v[(i2 + 1) * 26 + (j2 + 1)] =
        make_float4(acc[0] + b2[0], acc[1] + b2[1], acc[2] + b2[2], 0.f);
    __syncthreads();

    // ---- per-pixel SIFT: Sobel -> mag + 8-bin argmax bitmask (exact tie semantics) ----
    {
        const float C0c = 0.92387953f;  // cos(pi/8)
        const float C1c = 0.38268343f;  // cos(3pi/8)
        const float4* P = s2v + i2 * 26 + j2;
        float4 Pr[3][3];
#pragma unroll
        for (int r = 0; r < 3; ++r)
#pragma unroll
            for (int c = 0; c < 3; ++c) Pr[r][c] = P[r * 26 + c];

        float mg[3];
        unsigned int msk = 0u;
#pragma unroll
        for (int p = 0; p < 3; ++p) {
            const float p00 = f4c(Pr[0][0], p), p01 = f4c(Pr[0][1], p), p02 = f4c(Pr[0][2], p);
            const float p10 = f4c(Pr[1][0], p),                         p12 = f4c(Pr[1][2], p);
            const float p20 = f4c(Pr[2][0], p), p21 = f4c(Pr[2][1], p), p22 = f4c(Pr[2][2], p);
            const float Ix = (p02 - p00) + 2.f * (p12 - p10) + (p22 - p20);
            const float Iy = (p20 - p00) + 2.f * (p21 - p01) + (p22 - p02);
            mg[p] = sqrtf(Ix * Ix + Iy * Iy + 1e-12f);
            float cs[8];
            cs[0] =  C0c * Ix + C1c * Iy;
            cs[1] =  C1c * Ix + C0c * Iy;
            cs[2] = -C1c * Ix + C0c * Iy;
            cs[3] = -C0c * Ix + C1c * Iy;
            cs[4] = -C0c * Ix - C1c * Iy;
            cs[5] = -C1c * Ix - C0c * Iy;
            cs[6] =  C1c * Ix - C0c * Iy;
            cs[7] =  C0c * Ix - C1c * Iy;
            float cm = cs[0];
#pragma unroll
            for (int k = 1; k < 8; ++k) cm = fmaxf(cm, cs[k]);
#pragma unroll
            for (int k = 0; k < 8; ++k)
                if (cs[k] == cm) msk |= (1u << (p * 8 + k));
        }
        pm[i2 * 25 + j2] = make_float4(mg[0], mg[1], mg[2], __uint_as_float(msk));
    }
    __syncthreads();

    // ---- cell sums: 128 threads = (bin k, cell); no atomics ----
    if (t < 128) {
        const int k = t >> 4, cell = t & 15;
        const int r0 = (cell >> 2) * 6, c0p = (cell & 3) * 6;
        const float4* cp = pm + r0 * 25 + c0p;
        float s0 = 0.f, s1 = 0.f, s2 = 0.f;
#pragma unroll
        for (int r = 0; r < 6; ++r)
#pragma unroll
            for (int c = 0; c < 6; ++c) {
                const float4 v = cp[r * 25 + c];   // 4 lane-groups broadcast
                const unsigned int m = __float_as_uint(v.w);
                s0 += (m & (1u <<  k))       ? v.x : 0.f;
                s1 += (m & (1u << (8 + k)))  ? v.y : 0.f;
                s2 += (m & (1u << (16 + k))) ? v.z : 0.f;
            }
        hist[      k * 16 + cell] = s0;
        hist[128 + k * 16 + cell] = s1;
        hist[256 + k * 16 + cell] = s2;
    }
    __syncthreads();

    // ---- per-patch L2 norm (one wave per patch) ----
    if (t < 192) {
        const int p = t >> 6, l = t & 63;
        const float2 v = ((const float2*)(hist + p * 128))[l];
        float s = v.x * v.x + v.y * v.y;
#pragma unroll
        for (int off = 32; off; off >>= 1) s += __shfl_down(s, off);
        if (l == 0) nrm[p] = sqrtf(s) + 1e-8f;
    }
    __syncthreads();

    // ---- normalize + pow 0.9 ----
    if (t < 384) {
        const float v = hist[t] / nrm[t >> 7] + 1e-8f;
        hist[t] = __expf(0.9f * __logf(v));
    }
    __syncthreads();

    // ---- linear 384 -> 10 (16 lanes per output, float4) ----
    if (t < 160) {
        const int o = t >> 4, l = t & 15;
        const float4* hv = (const float4*)hist + l * 6;
        const float4* wv = (const float4*)(Wl + o * 384) + l * 6;
        float s = 0.f;
#pragma unroll
        for (int q = 0; q < 6; ++q) {
            const float4 h = hv[q], w = wv[q];
            s += h.x * w.x + h.y * w.y + h.z * w.z + h.w * w.w;
        }
#pragma unroll
        for (int off = 8; off; off >>= 1) s += __shfl_down(s, off, 16);
        if (l == 0) lg[o] = s + bl[o];
    }
    __syncthreads();

    // ---- relu + softmax ----
    if (t == 0) {
        float z[10], m = 0.f, ssum = 0.f;
#pragma unroll
        for (int o = 0; o < 10; ++o) { z[o] = fmaxf(lg[o], 0.f); m = fmaxf(m, z[o]); }
#pragma unroll
        for (int o = 0; o < 10; ++o) { z[o] = __expf(z[o] - m); ssum += z[o]; }
        const float inv = 1.f / ssum;
#pragma unroll
        for (int o = 0; o < 10; ++o) lg[o] = z[o] * inv;
    }
    __syncthreads();
    if (t < 10) out[n * 10 + t] = lg[t];
}

extern "C" void kernel_launch(void* const* d_in, const int* in_sizes, int n_in,
                              void* d_out, int out_size, void* d_ws, size_t ws_size,
                              hipStream_t stream) {
    const float* x  = (const float*)d_in[0];
    const float* W1 = (const float*)d_in[1];
    const float* b1 = (const float*)d_in[2];
    const float* W2 = (const float*)d_in[3];
    const float* b2 = (const float*)d_in[4];
    const float* Wl = (const float*)d_in[5];
    const float* bl = (const float*)d_in[6];
    float* out = (float*)d_out;
    const int N = in_sizes[0] / 784;  // 8192
    fused_pipeline<<<N, TPB, 0, stream>>>(x, W1, b1, W2, b2, Wl, bl, out);
}